// Round 5
// baseline (148.931 us; speedup 1.0000x reference)
//
#include <hip/hip_runtime.h>
#include <hip/hip_bf16.h>
#include <math.h>

// FeedForwardQuantum — Round 11: triple-buffer + counted vmcnt, ONE barrier
// per K-step (round-4's 8-barrier phase-split regressed; this keeps T4 but
// removes the phase overhead). prep/gemm1 verbatim round-0. gemm2:
//   256x128 tile, 512 thr / 8 waves (verified 64x64 cores), BK=64,
//   LDS = 3 buffers x 48 KiB = 144 KiB, 2-deep prefetch, vmcnt(6) in
//   steady state (never 0 until the tail), frag/epilogue index math
//   verbatim from the harness-verified round-4 build.

typedef __attribute__((ext_vector_type(8))) short short8;
typedef __attribute__((ext_vector_type(8))) unsigned short ushort8;
typedef __attribute__((ext_vector_type(4))) float fx4;

constexpr int EDIM = 512;
constexpr int FDIM = 2048;
constexpr int NQ   = 10;
constexpr int BK   = 64;
constexpr int BM2  = 256;          // gemm2 tile
constexpr int BN2  = 128;
constexpr int NT2  = FDIM / BK;    // 32 K-tiles
constexpr int ABUF = BM2 * BK;     // 16384 ushorts (32 KiB)
constexpr int BBUF = BN2 * BK;     // 8192 ushorts (16 KiB)

__device__ __forceinline__ ushort f2bf(float f) {
    union { float f; unsigned u; } v; v.f = f;
    unsigned u = v.u + 0x7FFFu + ((v.u >> 16) & 1u);
    return (ushort)(u >> 16);
}
__device__ __forceinline__ unsigned bits2(__hip_bfloat162 h) {
    union { __hip_bfloat162 h; unsigned u; } v; v.h = h; return v.u;
}
__device__ __forceinline__ void gload_lds16(const void* g, void* l) {
    __builtin_amdgcn_global_load_lds(
        (const __attribute__((address_space(1))) void*)g,
        (__attribute__((address_space(3))) void*)l, 16, 0, 0);
}

#define SBAR()   __builtin_amdgcn_s_barrier()
#define FENCE()  asm volatile("" ::: "memory")
#define VMCNT6() asm volatile("s_waitcnt vmcnt(6)" ::: "memory")
#define VMCNT0() asm volatile("s_waitcnt vmcnt(0)" ::: "memory")

// ---- prep: w2 f32 -> bf16 (verbatim round-0) ----
__global__ void prep(const float* __restrict__ w2, ushort* __restrict__ w2b) {
    int gid = blockIdx.x * blockDim.x + threadIdx.x;
    int np  = gridDim.x * blockDim.x;
    for (int i = gid; i < EDIM * FDIM / 4; i += np) {
        float4 v = ((const float4*)w2)[i];
        ushort4 o; o.x = f2bf(v.x); o.y = f2bf(v.y); o.z = f2bf(v.z); o.w = f2bf(v.w);
        ((ushort4*)w2b)[i] = o;
    }
}

// ---- gemm1 (verbatim round-0): h = relu(q @ w1^T + b1), bf16 out ----
__global__ __launch_bounds__(256, 2) void gemm1(
    const float* __restrict__ x, const float* __restrict__ rx,
    const float* __restrict__ w1, const float* __restrict__ b1,
    ushort* __restrict__ h, int m_base)
{
    __shared__ float qs[32][NQ];
    const int tid = threadIdx.x;
    const int m0  = m_base + blockIdx.x * 32;

    if (tid < 32) {
        const float* xr = x + (size_t)(m0 + tid) * EDIM;
        float c[NQ], q[NQ];
        #pragma unroll
        for (int w = 0; w < NQ; ++w) c[w] = cosf(xr[w] + rx[w]);
        float p0 = c[1];
        #pragma unroll
        for (int w = 2; w < NQ; ++w) p0 *= c[w];
        q[0] = p0;
        float p = c[0];
        #pragma unroll
        for (int w = 1; w < NQ; ++w) { p *= c[w]; q[w] = p; }
        #pragma unroll
        for (int w = 0; w < NQ; ++w) qs[tid][w] = q[w];
    }
    __syncthreads();

    float wv[80];
    {
        const float4* wp = (const float4*)(w1 + (size_t)tid * 80);
        #pragma unroll
        for (int u = 0; u < 20; ++u) ((float4*)wv)[u] = wp[u];
    }
    float bv[8];
    {
        float4 a = *(const float4*)(b1 + tid * 8);
        float4 b = *(const float4*)(b1 + tid * 8 + 4);
        bv[0]=a.x; bv[1]=a.y; bv[2]=a.z; bv[3]=a.w;
        bv[4]=b.x; bv[5]=b.y; bv[6]=b.z; bv[7]=b.w;
    }
    ushort* hrow = h + (size_t)m0 * FDIM + tid * 8;

    for (int m = 0; m < 32; ++m) {
        float qv[NQ];
        #pragma unroll
        for (int w = 0; w < NQ; ++w) qv[w] = qs[m][w];
        float a[8];
        #pragma unroll
        for (int r = 0; r < 8; ++r) a[r] = bv[r];
        #pragma unroll
        for (int w = 0; w < NQ; ++w)
            #pragma unroll
            for (int r = 0; r < 8; ++r)
                a[r] = fmaf(qv[w], wv[r * 10 + w], a[r]);
        ushort8 o;
        #pragma unroll
        for (int r = 0; r < 4; ++r) {
            unsigned p = bits2(__float22bfloat162_rn(
                make_float2(fmaxf(a[2*r], 0.f), fmaxf(a[2*r+1], 0.f))));
            o[2*r]   = (ushort)(p & 0xFFFFu);
            o[2*r+1] = (ushort)(p >> 16);
        }
        *(ushort8*)(hrow + (size_t)m * FDIM) = o;
    }
}

// ---- gemm2: out = h @ w2b^T + b2 — triple-buffer, 1 barrier/K-step ----
__global__ __launch_bounds__(512, 2) void gemm2(
    const ushort* __restrict__ h,     // [M][FDIM] bf16
    const ushort* __restrict__ w2b,   // [EDIM][FDIM] bf16
    const float* __restrict__ b2,
    float* __restrict__ out, int m_base)
{
    __shared__ __align__(16) ushort As[3 * ABUF];   // 96 KiB
    __shared__ __align__(16) ushort Bs[3 * BBUF];   // 48 KiB

    const int tid  = threadIdx.x;
    const int m0   = m_base + blockIdx.x * BM2;
    const int n0   = blockIdx.y * BN2;
    const int wave = tid >> 6, lane = tid & 63;
    const int quad = lane >> 4, l16 = lane & 15;
    const int wm   = wave >> 1, wn = wave & 1;      // 4x2 waves, 64x64 each
    const int swz  = l16 & 7;

    // staging roles (verbatim round-4): rows u*64 + (tid>>3), 16B-block bl
    const int srow = tid >> 3;
    const int bl   = (tid & 7) ^ (srow & 7);
    const ushort* pA[4]; const ushort* pB[2];
    #pragma unroll
    for (int u = 0; u < 4; ++u)
        pA[u] = h + (size_t)(m0 + u * 64 + srow) * FDIM + bl * 8;
    #pragma unroll
    for (int u = 0; u < 2; ++u)
        pB[u] = w2b + (size_t)(n0 + u * 64 + srow) * FDIM + bl * 8;

    // fragment-read row offsets (verbatim round-4, harness-verified)
    int aro[4], bro[4];
    #pragma unroll
    for (int t = 0; t < 4; ++t) {
        aro[t] = (wm * 64 + t * 16 + l16) * BK;
        bro[t] = (wn * 64 + t * 16 + l16) * BK;
    }

    fx4 acc[4][4];
    #pragma unroll
    for (int a = 0; a < 4; ++a)
        #pragma unroll
        for (int b = 0; b < 4; ++b) acc[a][b] = fx4{0.f, 0.f, 0.f, 0.f};

#define STAGE_A(dst) do { _Pragma("unroll") \
    for (int u = 0; u < 4; ++u) { gload_lds16(pA[u], (dst) + u * 4096 + wave * 512); pA[u] += BK; } } while(0)
#define STAGE_B(dst) do { _Pragma("unroll") \
    for (int u = 0; u < 2; ++u) { gload_lds16(pB[u], (dst) + u * 4096 + wave * 512); pB[u] += BK; } } while(0)
#define RDFRAGS(Ab, Bb, af, bf) do { _Pragma("unroll") \
    for (int t = 0; t < 4; ++t) _Pragma("unroll") \
    for (int hf = 0; hf < 2; ++hf) { \
        const int blk = (((hf * 4 + quad) ^ swz) << 3); \
        af[t][hf] = *(const short8*)&(Ab)[aro[t] + blk]; \
        bf[t][hf] = *(const short8*)&(Bb)[bro[t] + blk]; \
    } } while(0)
#define MMALL(af, bf) do { _Pragma("unroll") \
    for (int hf = 0; hf < 2; ++hf) _Pragma("unroll") \
    for (int mt = 0; mt < 4; ++mt) _Pragma("unroll") \
    for (int nt = 0; nt < 4; ++nt) \
        acc[mt][nt] = __builtin_amdgcn_mfma_f32_16x16x32_bf16( \
            af[mt][hf], bf[nt][hf], acc[mt][nt], 0, 0, 0); } while(0)

    // ---- prologue: stage tiles 0 (buf0) and 1 (buf1) ----
    STAGE_A(As); STAGE_B(Bs);
    STAGE_A(As + ABUF); STAGE_B(Bs + BBUF);
    VMCNT6();       // tile 0 landed; tile 1's 6 still in flight
    SBAR(); FENCE();

    // ---- main loop: t = 0..29; compute buf[cur], stage t+2 -> buf[stg] ----
    int cur = 0, stg = 2;
    for (int t = 0; t < NT2 - 2; ++t) {
        ushort* Aw = As + stg * ABUF;
        ushort* Bw = Bs + stg * BBUF;
        STAGE_A(Aw); STAGE_B(Bw);                   // tile t+2 in flight

        const ushort* Ab = As + cur * ABUF;
        const ushort* Bb = Bs + cur * BBUF;
        short8 af[4][2], bf[4][2];
        RDFRAGS(Ab, Bb, af, bf);
        __builtin_amdgcn_s_setprio(1);
        MMALL(af, bf);
        __builtin_amdgcn_s_setprio(0);

        VMCNT6();                                   // t+1 landed; t+2 in flight
        SBAR(); FENCE();
        cur = (cur == 2) ? 0 : cur + 1;
        stg = (stg == 2) ? 0 : stg + 1;
    }

    // ---- t = 30 (buf 0): compute, then drain tile 31 ----
    {
        short8 af[4][2], bf[4][2];
        RDFRAGS(As, Bs, af, bf);
        __builtin_amdgcn_s_setprio(1);
        MMALL(af, bf);
        __builtin_amdgcn_s_setprio(0);
        VMCNT0();                                   // tile 31 landed
        SBAR(); FENCE();
    }
    // ---- t = 31 (buf 1) ----
    {
        short8 af[4][2], bf[4][2];
        RDFRAGS(As + ABUF, Bs + BBUF, af, bf);
        __builtin_amdgcn_s_setprio(1);
        MMALL(af, bf);
        __builtin_amdgcn_s_setprio(0);
    }

#undef MMALL
#undef RDFRAGS
#undef STAGE_A
#undef STAGE_B

    // ---- epilogue: + b2 (verbatim round-4, harness-verified layout) ----
    float bb[4];
    #pragma unroll
    for (int nt = 0; nt < 4; ++nt) bb[nt] = b2[n0 + wn * 64 + nt * 16 + l16];
    #pragma unroll
    for (int mt = 0; mt < 4; ++mt) {
        const int mbase = m0 + wm * 64 + mt * 16 + quad * 4;
        #pragma unroll
        for (int nt = 0; nt < 4; ++nt) {
            const int n = n0 + wn * 64 + nt * 16 + l16;
            #pragma unroll
            for (int r = 0; r < 4; ++r)
                out[(size_t)(mbase + r) * EDIM + n] = acc[mt][nt][r] + bb[nt];
        }
    }
}

extern "C" void kernel_launch(void* const* d_in, const int* in_sizes, int n_in,
                              void* d_out, int out_size, void* d_ws, size_t ws_size,
                              hipStream_t stream) {
    const float* x  = (const float*)d_in[0];
    const float* rx = (const float*)d_in[1];
    const float* w1 = (const float*)d_in[2];
    const float* b1 = (const float*)d_in[3];
    const float* w2 = (const float*)d_in[4];
    const float* b2 = (const float*)d_in[5];
    float* out = (float*)d_out;

    const int M = in_sizes[0] / EDIM;   // 16384

    const size_t w2bytes = (size_t)EDIM * FDIM * 2;
    ushort* w2b = (ushort*)d_ws;
    ushort* h   = (ushort*)((char*)d_ws + w2bytes);

    int Ms = M;   // slice if ws can't hold full h (full M needs 64 MiB)
    {
        size_t avail = (ws_size > w2bytes) ? ws_size - w2bytes : 0;
        int cap = (int)(avail / ((size_t)FDIM * 2));
        cap &= ~255;
        if (cap < 256) cap = 256;
        if (Ms > cap) Ms = cap;
    }

    hipLaunchKernelGGL(prep, dim3(256), dim3(256), 0, stream, w2, w2b);

    for (int mb = 0; mb < M; mb += Ms) {
        int cur = (M - mb < Ms) ? (M - mb) : Ms;
        hipLaunchKernelGGL(gemm1, dim3(cur / 32), dim3(256), 0, stream,
                           x, rx, w1, b1, h, mb);
        hipLaunchKernelGGL(gemm2, dim3(cur / BM2, EDIM / BN2), dim3(512), 0, stream,
                           h, w2b, b2, out, mb);
    }
}

// Round 6
// 138.641 us; speedup vs baseline: 1.0742x; 1.0742x over previous
//
#include <hip/hip_runtime.h>
#include <hip/hip_bf16.h>
#include <math.h>

// FeedForwardQuantum — Round 12: single fused kernel, h produced IN-LDS by a
// split-precision K=32 MFMA (Z=[q_hi|q_lo|q_hi|1|1], W=[w1_hi|w1_hi|w1_lo|b1_hi|b1_lo]
// => fp32-accurate h in one mfma, then same RNE bf16 pack as gemm1).
// Eliminates gemm1 (11.9us of pure h-write BW) AND gemm2's HBM-A staging
// latency (FETCH 41MB -> ~5MB). gemm2 core/B-staging/epilogue are VERBATIM
// round-0 (harness-verified): 128x128 tile, 256 thr, 4 waves, 2 blocks/CU,
// now double-buffered (72 KiB LDS). w1-frags register-prefetched 1 chunk ahead.

typedef __attribute__((ext_vector_type(8))) short short8;
typedef __attribute__((ext_vector_type(8))) unsigned short ushort8;
typedef __attribute__((ext_vector_type(4))) float fx4;

constexpr int EDIM = 512;
constexpr int FDIM = 2048;
constexpr int NQ   = 10;
constexpr int BK   = 64;
constexpr int BM   = 128;
constexpr int BN   = 128;
constexpr int NCH  = FDIM / BK;   // 32

__device__ __forceinline__ ushort f2bf(float f) {   // f32 -> bf16 RNE
    union { float f; unsigned u; } v; v.f = f;
    unsigned u = v.u + 0x7FFFu + ((v.u >> 16) & 1u);
    return (ushort)(u >> 16);
}
__device__ __forceinline__ float bf2f(ushort u) {
    union { unsigned u; float f; } v; v.u = (unsigned)u << 16; return v.f;
}
__device__ __forceinline__ unsigned bits2(__hip_bfloat162 h) {
    union { __hip_bfloat162 h; unsigned u; } v; v.h = h; return v.u;
}
__device__ __forceinline__ void gload_lds16(const void* g, void* l) {
    __builtin_amdgcn_global_load_lds(
        (const __attribute__((address_space(1))) void*)g,
        (__attribute__((address_space(3))) void*)l, 16, 0, 0);
}

// ---- prep: w2 f32->bf16 (verbatim round-0) + split-precision w1t build ----
__global__ void prep(const float* __restrict__ w2, const float* __restrict__ w1,
                     const float* __restrict__ b1,
                     ushort* __restrict__ w2b, ushort* __restrict__ w1t) {
    int gid = blockIdx.x * blockDim.x + threadIdx.x;
    int np  = gridDim.x * blockDim.x;
    for (int i = gid; i < EDIM * FDIM / 4; i += np) {
        float4 v = ((const float4*)w2)[i];
        ushort4 o; o.x = f2bf(v.x); o.y = f2bf(v.y); o.z = f2bf(v.z); o.w = f2bf(v.w);
        ((ushort4*)w2b)[i] = o;
    }
    for (int f = gid; f < FDIM; f += np) {
        ushort zr[32];
        #pragma unroll
        for (int w = 0; w < NQ; ++w) {
            float v  = w1[f * NQ + w];
            ushort hb = f2bf(v);
            ushort lb = f2bf(v - bf2f(hb));
            zr[w] = hb; zr[10 + w] = hb; zr[20 + w] = lb;
        }
        float bv  = b1[f];
        ushort bh = f2bf(bv);
        zr[30] = bh; zr[31] = f2bf(bv - bf2f(bh));
        #pragma unroll
        for (int u = 0; u < 4; ++u)
            *(ushort8*)&w1t[f * 32 + u * 8] = *(ushort8*)&zr[u * 8];
    }
}

// ---- fused: out = relu(q@w1^T+b1) @ w2^T + b2 ----
__global__ __launch_bounds__(256, 2) void fused(
    const float* __restrict__ x, const float* __restrict__ rx,
    const ushort* __restrict__ w1t,   // [FDIM][32] bf16 split-precision
    const ushort* __restrict__ w2b,   // [EDIM][FDIM] bf16
    const float* __restrict__ b2,
    float* __restrict__ out)
{
    __shared__ __align__(16) ushort Zs[BM * 32];       // 8 KiB
    __shared__ __align__(16) ushort As[2][BM * BK];    // 32 KiB (h tiles)
    __shared__ __align__(16) ushort Bs[2][BN * BK];    // 32 KiB (w2 tiles)

    const int tid = threadIdx.x;
    const int m0  = blockIdx.x * BM;
    const int n0  = blockIdx.y * BN;

    // ---- q prologue (verbatim round-0 math) -> split bf16 Z rows ----
    if (tid < BM) {
        const float* xr = x + (size_t)(m0 + tid) * EDIM;
        float4 xa = *(const float4*)xr;
        float4 xb = *(const float4*)(xr + 4);
        float2 xc = *(const float2*)(xr + 8);
        float xv[NQ] = {xa.x, xa.y, xa.z, xa.w, xb.x, xb.y, xb.z, xb.w, xc.x, xc.y};
        float c[NQ], q[NQ];
        #pragma unroll
        for (int w = 0; w < NQ; ++w) c[w] = cosf(xv[w] + rx[w]);
        float p0 = c[1];
        #pragma unroll
        for (int w = 2; w < NQ; ++w) p0 *= c[w];
        q[0] = p0;
        float p = c[0];
        #pragma unroll
        for (int w = 1; w < NQ; ++w) { p *= c[w]; q[w] = p; }
        ushort zr[32];
        #pragma unroll
        for (int w = 0; w < NQ; ++w) {
            ushort hb = f2bf(q[w]);
            ushort lb = f2bf(q[w] - bf2f(hb));
            zr[w] = hb; zr[10 + w] = lb; zr[20 + w] = hb;
        }
        zr[30] = 0x3F80u; zr[31] = 0x3F80u;   // 1.0, 1.0 (pair with b1_hi/b1_lo)
        #pragma unroll
        for (int u = 0; u < 4; ++u)
            *(ushort8*)&Zs[tid * 32 + u * 8] = *(ushort8*)&zr[u * 8];
    }
    __syncthreads();

    const int wave = tid >> 6, lane = tid & 63;
    const int quad = lane >> 4, l16 = lane & 15;
    const int wm   = wave >> 1, wn = wave & 1;    // gemm2 core: 2x2 waves, 64x64
    const int swz  = l16 & 7;

    // H-production roles (independent of gemm2-core mapping):
    const int hm0 = (wave & 1) * 64;              // wave's 64 m-rows for HPROD... 
    const int hf0 = (wave >> 1) * 32;             // wave's 32-f slice
    // zfrags: 4 x 16 m-rows, persistent
    short8 zf[4];
    #pragma unroll
    for (int mi = 0; mi < 4; ++mi)
        zf[mi] = *(const short8*)&Zs[(hm0 + mi * 16 + l16) * 32 + quad * 8];

    // B staging (verbatim round-0)
    const int srow0 = tid >> 3;
    const int sbs   = tid & 7;
    const ushort* gB[4];
    #pragma unroll
    for (int u = 0; u < 4; ++u) {
        int row = u * 32 + srow0;
        int bl  = sbs ^ (row & 7);
        gB[u] = w2b + (size_t)(n0 + row) * FDIM + bl * 8;
    }
    const int ldst = wave * 512;

    // fragment-read offsets (verbatim round-0)
    int aro[4], bro[4];
    #pragma unroll
    for (int t = 0; t < 4; ++t) {
        aro[t] = (wm * 64 + t * 16 + l16) * BK;
        bro[t] = (wn * 64 + t * 16 + l16) * BK;
    }

    fx4 acc[4][4];
    #pragma unroll
    for (int a = 0; a < 4; ++a)
        #pragma unroll
        for (int b = 0; b < 4; ++b) acc[a][b] = fx4{0.f, 0.f, 0.f, 0.f};

    short8 wfE[2], wfO[2];

#define WLOAD(WF, CH) do { _Pragma("unroll") \
    for (int fi = 0; fi < 2; ++fi) \
        WF[fi] = *(const short8*)(w1t + ((CH) * 64 + hf0 + fi * 16 + l16) * 32 + quad * 8); \
} while (0)

#define STAGEB(BUF) do { _Pragma("unroll") \
    for (int u = 0; u < 4; ++u) { gload_lds16(gB[u], &Bs[BUF][u * 2048 + ldst]); gB[u] += BK; } \
} while (0)

// H-tile for one chunk -> As[BUF]: h = mfma(W,Z): D row(quad*4+r)=f, col(l16)=m
#define HPROD(BUF, WF) do { _Pragma("unroll") \
    for (int mi = 0; mi < 4; ++mi) { \
        const int hrow = hm0 + mi * 16 + l16; \
        ushort* arow = &As[BUF][hrow * BK]; \
        _Pragma("unroll") \
        for (int fi = 0; fi < 2; ++fi) { \
            fx4 hv = __builtin_amdgcn_mfma_f32_16x16x32_bf16( \
                WF[fi], zf[mi], fx4{0.f, 0.f, 0.f, 0.f}, 0, 0, 0); \
            unsigned ua = bits2(__float22bfloat162_rn( \
                make_float2(fmaxf(hv[0], 0.f), fmaxf(hv[1], 0.f)))); \
            unsigned ub = bits2(__float22bfloat162_rn( \
                make_float2(fmaxf(hv[2], 0.f), fmaxf(hv[3], 0.f)))); \
            const int blk = (hf0 >> 3) + fi * 2 + (quad >> 1); \
            *(uint2*)&arow[((blk ^ swz) << 3) + ((quad & 1) << 2)] = make_uint2(ua, ub); \
        } \
    } \
} while (0)

#define COMPUTE(BUF) do { \
    short8 af[4][2], bf[4][2]; \
    _Pragma("unroll") \
    for (int t = 0; t < 4; ++t) \
        _Pragma("unroll") \
        for (int hf = 0; hf < 2; ++hf) { \
            const int blkb = (((hf * 4 + quad) ^ swz) << 3); \
            af[t][hf] = *(const short8*)&As[BUF][aro[t] + blkb]; \
            bf[t][hf] = *(const short8*)&Bs[BUF][bro[t] + blkb]; \
        } \
    _Pragma("unroll") \
    for (int hf = 0; hf < 2; ++hf) \
        _Pragma("unroll") \
        for (int mt = 0; mt < 4; ++mt) \
            _Pragma("unroll") \
            for (int nt = 0; nt < 4; ++nt) \
                acc[mt][nt] = __builtin_amdgcn_mfma_f32_16x16x32_bf16( \
                    af[mt][hf], bf[nt][hf], acc[mt][nt], 0, 0, 0); \
} while (0)

    // ---- prologue: chunk 0 -> buf0; prefetch w-frags for chunk 1 ----
    STAGEB(0);
    WLOAD(wfE, 0);
    HPROD(0, wfE);
    WLOAD(wfO, 1);
    __syncthreads();

    // ---- main loop: 15 pairs; chunk c lives in buf c&1 ----
    for (int p = 0; p < 15; ++p) {
        STAGEB(1); HPROD(1, wfO); WLOAD(wfE, 2 * p + 2);   // chunk 2p+1 build
        COMPUTE(0);                                         // chunk 2p
        __syncthreads();
        STAGEB(0); HPROD(0, wfE); WLOAD(wfO, 2 * p + 3);   // chunk 2p+2 build
        COMPUTE(1);                                         // chunk 2p+1
        __syncthreads();
    }
    // ---- tails: chunk 31 build, chunks 30 & 31 compute ----
    STAGEB(1); HPROD(1, wfO);
    COMPUTE(0);
    __syncthreads();
    COMPUTE(1);

#undef COMPUTE
#undef HPROD
#undef STAGEB
#undef WLOAD

    // ---- epilogue: + b2 (verbatim round-0, harness-verified layout) ----
    float bb[4];
    #pragma unroll
    for (int nt = 0; nt < 4; ++nt) bb[nt] = b2[n0 + wn * 64 + nt * 16 + l16];
    #pragma unroll
    for (int mt = 0; mt < 4; ++mt) {
        const int mbase = m0 + wm * 64 + mt * 16 + quad * 4;
        #pragma unroll
        for (int nt = 0; nt < 4; ++nt) {
            const int n = n0 + wn * 64 + nt * 16 + l16;
            #pragma unroll
            for (int r = 0; r < 4; ++r)
                out[(size_t)(mbase + r) * EDIM + n] = acc[mt][nt][r] + bb[nt];
        }
    }
}

extern "C" void kernel_launch(void* const* d_in, const int* in_sizes, int n_in,
                              void* d_out, int out_size, void* d_ws, size_t ws_size,
                              hipStream_t stream) {
    const float* x  = (const float*)d_in[0];
    const float* rx = (const float*)d_in[1];
    const float* w1 = (const float*)d_in[2];
    const float* b1 = (const float*)d_in[3];
    const float* w2 = (const float*)d_in[4];
    const float* b2 = (const float*)d_in[5];
    float* out = (float*)d_out;

    const int M = in_sizes[0] / EDIM;   // 16384

    ushort* w2b = (ushort*)d_ws;                                   // 2 MiB
    ushort* w1t = (ushort*)((char*)d_ws + (size_t)EDIM * FDIM * 2); // 128 KiB
    (void)ws_size; (void)n_in; (void)out_size;

    hipLaunchKernelGGL(prep, dim3(256), dim3(256), 0, stream, w2, w1, b1, w2b, w1t);
    hipLaunchKernelGGL(fused, dim3(M / BM, EDIM / BN), dim3(256), 0, stream,
                       x, rx, w1t, w2b, b2, out);
}